// Round 11
// baseline (122.756 us; speedup 1.0000x reference)
//
#include <hip/hip_runtime.h>

// B=64, K=8, H=W=128 (HW=16384). float32 in/out.
// out[0] = loss scalar; out[1..] = pred_perm (B,K,H,W) flat.
//
// Fence-free 2-dispatch pipeline (no memsets, no extra launches):
//   cost_kernel    : 1024 blocks; double-buffered global_load_lds staging; partial
//                    cross[i][j]/ent[j] sums; ONE 18-value butterfly per wave.
//                    Block 0 zeroes out[0] for the loss atomics. (Best measured
//                    across 8 structural variants, ~38 us plateau.)
//   permute_kernel : 512 blocks (full row each): fused Held-Karp DP (redundant per
//                    block, parallel) + permuted copy with aligned float4 stores;
//                    one block per batch atomicAdds the batch loss into out[0].
//
// Measured dead-ends (do not revisit): per-block __threadfence+atomic completion
// protocols (R5/R6: +70..170 us, scales with fencing block count); cooperative
// grid.sync (R10: launch fails under graph capture); register double-buffering
// (R5: VGPR 192 -> occupancy collapse); 4096-block cost grids (R4/R7: DS-pipe
// butterfly overhead); 3-dispatch layouts (R7: boundary costs ~10 us).

#define BB 64
#define KK 8
#define HW 16384
#define SPANS 16     // cost blocks per batch
#define SPAN 1024    // floats per span per row
#define NCH 4        // 256-float chunks per span
#define CHUNK 256
#define EPSF 1e-15f

// ---------- compile-time mask table: all 255 nonzero 8-bit masks, level-ordered by popcount ----------
struct MaskTab {
    unsigned char masks[255];
    int off[9];
};

constexpr MaskTab make_tab() {
    MaskTab t{};
    int idx = 0;
    for (int p = 1; p <= 8; ++p) {
        t.off[p - 1] = idx;
        for (int m = 1; m < 256; ++m) {
            int c = 0;
            for (int b = 0; b < 8; ++b) c += (m >> b) & 1;
            if (c == p) t.masks[idx++] = (unsigned char)m;
        }
    }
    t.off[8] = idx;
    return t;
}

__constant__ MaskTab kTab = make_tab();

__device__ __forceinline__ float dot4(float4 t, float4 l) {
    return t.x * l.x + t.y * l.y + t.z * l.z + t.w * l.w;
}

__device__ __forceinline__ float4 log4(float4 a) {
    float4 r;
    r.x = __logf(a.x + EPSF); r.y = __logf(a.y + EPSF);
    r.z = __logf(a.z + EPSF); r.w = __logf(a.w + EPSF);
    return r;
}

// ---------- phase 1: partial cross/ent sums, double-buffered LDS staging ----------
__global__ __launch_bounds__(256) void cost_kernel(const float* __restrict__ pred,
                                                   const float* __restrict__ aug,
                                                   float* __restrict__ part,   // [1024][72]
                                                   float* __restrict__ out)
{
    __shared__ float tile[2][16][CHUNK];

    const int blk  = blockIdx.x;        // b*SPANS + s
    const int b    = blk >> 4;
    const int s    = blk & 15;
    const int tid  = threadIdx.x;
    const int wave = tid >> 6;
    const int lane = tid & 63;

    if (blk == 0 && tid == 0) out[0] = 0.f;   // loss accumulator init (pre-atomics)

    const size_t base = (size_t)b * (KK * HW) + (size_t)s * SPAN;
    const int e4 = lane * 4;
    const int w2 = 2 * wave;

#define STAGE(c)                                                                          \
    {                                                                                     \
        const int pb_ = (c) & 1;                                                          \
        _Pragma("unroll")                                                                 \
        for (int m = 0; m < 4; ++m) {                                                     \
            const int vr = wave + 4 * m;                                                  \
            const float* g = ((vr < 8) ? (pred + base + (size_t)vr * HW)                  \
                                       : (aug + base + (size_t)(vr - 8) * HW))            \
                             + (c) * CHUNK + e4;                                          \
            __builtin_amdgcn_global_load_lds(                                             \
                (const __attribute__((address_space(1))) void*)g,                         \
                (__attribute__((address_space(3))) void*)&tile[pb_][vr][e4], 16, 0, 0);   \
        }                                                                                 \
    }

    STAGE(0)

    float acc[16];
#pragma unroll
    for (int v = 0; v < 16; ++v) acc[v] = 0.f;
    float e0 = 0.f, e1 = 0.f;

#pragma unroll
    for (int c = 0; c < NCH; ++c) {
        __syncthreads();                 // drains vmcnt: stage(c) landed
        if (c + 1 < NCH) STAGE(c + 1)    // async into the other buffer, overlaps compute

        const int pb = c & 1;
        const float4 la = log4(*(const float4*)&tile[pb][w2][e4]);
        const float4 lc = log4(*(const float4*)&tile[pb][w2 + 1][e4]);
#pragma unroll
        for (int j = 0; j < 8; ++j) {
            const float4 tv = *(const float4*)&tile[pb][8 + j][e4];
            acc[j]     += dot4(tv, la);
            acc[8 + j] += dot4(tv, lc);
            if (j == w2)     e0 += dot4(tv, log4(tv));   // wave-uniform branch
            if (j == w2 + 1) e1 += dot4(tv, log4(tv));
        }
    }
#undef STAGE

    // one 18-value wave butterfly per wave
#pragma unroll
    for (int v = 0; v < 16; ++v) {
        float sv = acc[v];
#pragma unroll
        for (int d = 1; d < 64; d <<= 1) sv += __shfl_xor(sv, d);
        acc[v] = sv;
    }
#pragma unroll
    for (int d = 1; d < 64; d <<= 1) e0 += __shfl_xor(e0, d);
#pragma unroll
    for (int d = 1; d < 64; d <<= 1) e1 += __shfl_xor(e1, d);

    if (lane == 0) {
        float* dst = part + (size_t)blk * 72;
#pragma unroll
        for (int j = 0; j < 8; ++j) {
            dst[16 * wave + j]     = acc[j];       // cross[i=2w][j]
            dst[16 * wave + 8 + j] = acc[8 + j];   // cross[i=2w+1][j]
        }
        dst[64 + w2]     = e0;                     // ent[2w]
        dst[64 + w2 + 1] = e1;                     // ent[2w+1]
    }
}

// ---------- phase 2: fused DP + permuted copy (512 blocks, full row each) ----------
// grid: 512 blocks of 256 threads; block p handles pair p = b*8 + jcol (one full
// 16384-float row). Each block redundantly reduces its batch's 16 span-partials and
// runs the Held-Karp DP (~parallel). Block p==b*8 atomicAdds the batch loss.
// Stores: out+1 row base is 4B-aligned; element 3 of each row is 16B-aligned ->
// middle 4095 quads as aligned float4; head 3 + tail 1 scalar by one thread.
__global__ __launch_bounds__(256) void permute_kernel(const float* __restrict__ pred,
                                                      const float* __restrict__ part,
                                                      float* __restrict__ out)
{
    __shared__ float red[72];
    __shared__ float C[64];     // C[i*8+j] = ent[j] - cross[i][j] (unscaled)
    __shared__ float dp[256];
    __shared__ int   choice[256];
    __shared__ int   inv8[8];   // col -> src row

    const int p    = blockIdx.x;   // pair = b*8 + jcol
    const int b    = p >> 3;
    const int tid  = threadIdx.x;

    // --- reduce the 16 span-partials for batch b ---
    const float* pb = part + (size_t)b * SPANS * 72;
    if (tid < 72) {
        float s = 0.f;
#pragma unroll
        for (int c = 0; c < SPANS; ++c) s += pb[c * 72 + tid];
        red[tid] = s;
    }
    if (tid == 0) dp[0] = 0.f;
    __syncthreads();
    if (tid < 64) C[tid] = red[64 + (tid & 7)] - red[tid];
    __syncthreads();

    // --- Held-Karp DP over 255 masks, level-ordered; 32 mask slots per pass ---
    const int grp = tid >> 3;
    const int j   = tid & 7;
    for (int lvl = 1; lvl <= 8; ++lvl) {
        const int start = kTab.off[lvl - 1];
        const int end   = kTab.off[lvl];
        const float* Crow = &C[(lvl - 1) * 8];
        for (int bse = start; bse < end; bse += 32) {
            const int mi = bse + grp;
            if (mi < end) {
                const int M = kTab.masks[mi];
                float v  = 1e30f;
                int   bj = 0;
                if (M & (1 << j)) {
                    v  = dp[M ^ (1 << j)] + Crow[j];
                    bj = j;
                }
#pragma unroll
                for (int d = 1; d < 8; d <<= 1) {
                    const float ov = __shfl_xor(v, d);
                    const int   oj = __shfl_xor(bj, d);
                    if (ov < v) { v = ov; bj = oj; }
                }
                if (j == 0) { dp[M] = v; choice[M] = bj; }
            }
        }
        __syncthreads();
    }

    if (tid == 0) {
        int mask = 255;
        for (int r = 7; r >= 0; --r) {
            const int jj = choice[mask];
            inv8[jj] = r;              // column jj takes pred row r
            mask ^= 1 << jj;
        }
        if ((p & 7) == 0)              // one designated block per batch
            atomicAdd(out, dp[255] * (1.0f / (16384.0f * 512.0f)));
    }
    __syncthreads();

    // --- permuted copy of the full row (16384 elements = 4096 quads) ---
    const int src_row = inv8[p & 7];   // uniform per block
    const float* src  = pred + ((size_t)(b << 3) + src_row) * HW;
    float*      drow  = out + 1 + (size_t)p * HW;

#pragma unroll
    for (int m = 0; m < 16; ++m) {
        const int f = tid + 256 * m;              // quad index in [0,4096)
        const int e = 3 + 4 * f;
        if (f < 4095) {
            float4 v;
            v.x = src[e]; v.y = src[e + 1]; v.z = src[e + 2]; v.w = src[e + 3];
            *(float4*)(drow + e) = v;             // 16B-aligned
        } else {                                  // f==4095: head 3 + tail 1
            drow[0] = src[0]; drow[1] = src[1]; drow[2] = src[2];
            drow[16383] = src[16383];
        }
    }
}

extern "C" void kernel_launch(void* const* d_in, const int* in_sizes, int n_in,
                              void* d_out, int out_size, void* d_ws, size_t ws_size,
                              hipStream_t stream) {
    const float* pred = (const float*)d_in[0];
    const float* aug  = (const float*)d_in[1];
    float* out = (float*)d_out;
    float* part = (float*)d_ws;                      // 1024*72 floats

    cost_kernel<<<dim3(BB * SPANS), dim3(256), 0, stream>>>(pred, aug, part, out);
    permute_kernel<<<dim3(512), dim3(256), 0, stream>>>(pred, part, out);
}